// Round 17
// baseline (60.660 us; speedup 1.0000x reference)
//
#include <hip/hip_runtime.h>
#include <hip/hip_bf16.h>
#include <float.h>
#include <stdint.h>

#define NPTS 8192
#define SEG  2048
#define CF   16
#define HID1 64
#define HID2 128
#define KMAX 64
#define R2   0.49f
#define CAP  384          // max in-radius candidates ~170 expected; wide margin
#define NCH  6            // CAP / 64

typedef unsigned long long ULL;
typedef short bf16x8 __attribute__((ext_vector_type(8)));
typedef float f32x4  __attribute__((ext_vector_type(4)));

__device__ __forceinline__ uint32_t f2ord(float f) {
    uint32_t u = __float_as_uint(f);
    return (u & 0x80000000u) ? ~u : (u | 0x80000000u);
}

// native RNE f32 -> bf16 (hardware v_cvt; identical bits to manual RNE for finite)
__device__ __forceinline__ short f2bf(float f) {
    __hip_bfloat16 h = __float2bfloat16(f);
    union { __hip_bfloat16 b; short s; } u; u.b = h;
    return u.s;
}

// ---- prep: A = x@W1[:16] + pos@W1[16:19] + b1 ; C = pos@W1[16:19] ;
//      pos4 = (x,y,z,sq) ; W2T[c][k] = bf16(W2[k][c]) ; echo pos/batch ----
__global__ __launch_bounds__(256) void prep_kernel(
    const float* __restrict__ x, const float* __restrict__ pos,
    const int* __restrict__ batch,
    const float* __restrict__ W1, const float* __restrict__ b1,
    const float* __restrict__ W2,
    float* __restrict__ A, float* __restrict__ C,
    float4* __restrict__ pos4, unsigned short* __restrict__ W2T,
    float* __restrict__ out)
{
    const int t = blockIdx.x * 256 + threadIdx.x;   // t < NPTS*64
    const int i = t >> 6, k = t & 63;

    const float px = pos[3 * i + 0], py = pos[3 * i + 1], pz = pos[3 * i + 2];
    float c = __fmul_rn(px, W1[16 * HID1 + k]);
    c = fmaf(py, W1[17 * HID1 + k], c);
    c = fmaf(pz, W1[18 * HID1 + k], c);

    float a = b1[k];
    #pragma unroll
    for (int cc = 0; cc < CF; ++cc)
        a = fmaf(x[i * CF + cc], W1[cc * HID1 + k], a);
    a += c;

    A[t] = a;
    C[t] = c;

    if (t < HID1 * HID2) {
        const int cc = t >> 6, kk = t & 63;      // W2T[c][k], c-stride 64
        W2T[t] = (unsigned short)f2bf(W2[kk * HID2 + cc]);
    }

    if (k == 0) {
        const float sq = __fadd_rn(__fadd_rn(__fmul_rn(px, px), __fmul_rn(py, py)),
                                   __fmul_rn(pz, pz));
        pos4[i] = make_float4(px, py, pz, sq);
    }
    if (k < 3) out[NPTS * HID2 + 3 * i + k] = pos[3 * i + k];
    if (k == 3) out[NPTS * HID2 + NPTS * 3 + i] = (float)batch[i];
}

// ---- 1 wave = 2 centroids: hoisted cv loads -> depth-8 double-buffered scan ->
//      fused dual threshold select -> hoisted dual af build -> shared-B MFMA ----
__global__ __launch_bounds__(64, 3) void pointconv_kernel(
    const int* __restrict__ batch,
    const unsigned short* __restrict__ W2T, const float* __restrict__ b2,
    const float* __restrict__ A, const float* __restrict__ C,
    const float4* __restrict__ pos4, float* __restrict__ out)
{
    __shared__ ULL s_key[2][CAP];   // 6 KB
    __shared__ int s_nbr[2][KMAX];  // 512 B

    const int l  = threadIdx.x;
    const int i0 = blockIdx.x * 2;          // pair shares a segment (2048 even)
    const int r = l & 15, q = l >> 4;

    const float4 cw0 = pos4[i0], cw1 = pos4[i0 + 1];
    const int seg0 = batch[i0] * SEG;
    const ULL lmask = (1ull << l) - 1ull;

    // hoisted C-row loads (independent of everything below; overlap with scan)
    float cv[2][2][8];
    #pragma unroll
    for (int ci = 0; ci < 2; ++ci) {
        const float4* Cv = (const float4*)(C + (size_t)(i0 + ci) * HID1);
        #pragma unroll
        for (int kc = 0; kc < 2; ++kc) {
            const float4 c0 = Cv[kc * 8 + q * 2], c1 = Cv[kc * 8 + q * 2 + 1];
            cv[ci][kc][0] = c0.x; cv[ci][kc][1] = c0.y;
            cv[ci][kc][2] = c0.z; cv[ci][kc][3] = c0.w;
            cv[ci][kc][4] = c1.x; cv[ci][kc][5] = c1.y;
            cv[ci][kc][6] = c1.z; cv[ci][kc][7] = c1.w;
        }
    }

    // ---- scan: depth-8 double-buffered load pipeline (all-static indexing) ----
    int cnt0 = 0, cnt1 = 0;
    {
        float4 buf[2][8];
        #pragma unroll
        for (int k = 0; k < 8; ++k) buf[0][k] = pos4[seg0 + k * 64 + l];

        #pragma unroll
        for (int g = 0; g < 4; ++g) {                 // 4 groups x 8 iters = 32
            const int cur = g & 1, nxt = cur ^ 1;
            if (g < 3) {
                #pragma unroll
                for (int k = 0; k < 8; ++k)
                    buf[nxt][k] = pos4[seg0 + ((g + 1) * 8 + k) * 64 + l];
            }
            #pragma unroll
            for (int k = 0; k < 8; ++k) {
                const float4 cur4 = buf[cur][k];
                const int j = seg0 + (g * 8 + k) * 64 + l;
                const float dot0 = fmaf(cw0.z, cur4.z, fmaf(cw0.y, cur4.y, __fmul_rn(cw0.x, cur4.x)));
                const float d20  = __fsub_rn(__fadd_rn(cw0.w, cur4.w), __fmul_rn(2.0f, dot0));
                const float dot1 = fmaf(cw1.z, cur4.z, fmaf(cw1.y, cur4.y, __fmul_rn(cw1.x, cur4.x)));
                const float d21  = __fsub_rn(__fadd_rn(cw1.w, cur4.w), __fmul_rn(2.0f, dot1));
                const bool h0 = (d20 <= R2), h1 = (d21 <= R2);
                const ULL m0 = __ballot(h0), m1 = __ballot(h1);
                if (h0) {
                    const int p = cnt0 + __popcll(m0 & lmask);
                    if (p < CAP) s_key[0][p] = ((ULL)f2ord(d20) << 32) | (unsigned)j;
                }
                cnt0 += __popcll(m0);
                if (h1) {
                    const int p = cnt1 + __popcll(m1 & lmask);
                    if (p < CAP) s_key[1][p] = ((ULL)f2ord(d21) << 32) | (unsigned)j;
                }
                cnt1 += __popcll(m1);
            }
        }
    }
    if (cnt0 > CAP) cnt0 = CAP;
    if (cnt1 > CAP) cnt1 = CAP;
    const bool nd0 = cnt0 > KMAX, nd1 = cnt1 > KMAX;

    uint32_t eo0[NCH], ej0[NCH], eo1[NCH], ej1[NCH];
    if (!nd0) {
        if (l < KMAX) s_nbr[0][l] = (l < cnt0) ? (int)(s_key[0][l] & 0xffffffffu) : i0;
    } else {
        #pragma unroll
        for (int g = 0; g < NCH; ++g) {
            eo0[g] = 0xffffffffu; ej0[g] = 0xffffffffu;
            if (64 * g < cnt0) {
                const int e = l + 64 * g;
                if (e < cnt0) {
                    const ULL kk = s_key[0][e];
                    eo0[g] = (uint32_t)(kk >> 32);
                    ej0[g] = (uint32_t)(kk & 0xffffffffu);
                }
            }
        }
    }
    if (!nd1) {
        if (l < KMAX) s_nbr[1][l] = (l < cnt1) ? (int)(s_key[1][l] & 0xffffffffu) : i0 + 1;
    } else {
        #pragma unroll
        for (int g = 0; g < NCH; ++g) {
            eo1[g] = 0xffffffffu; ej1[g] = 0xffffffffu;
            if (64 * g < cnt1) {
                const int e = l + 64 * g;
                if (e < cnt1) {
                    const ULL kk = s_key[1][e];
                    eo1[g] = (uint32_t)(kk >> 32);
                    ej1[g] = (uint32_t)(kk & 0xffffffffu);
                }
            }
        }
    }

    if (nd0 || nd1) {
        const uint32_t ORDR2 = 0x80000000u | __float_as_uint(R2);
        // fused dual binary search (independent chains -> in-wave ILP)
        uint32_t lo0 = 0u, hi0 = nd0 ? ORDR2 : 0u;
        uint32_t lo1 = 0u, hi1 = nd1 ? ORDR2 : 0u;
        while ((lo0 < hi0) | (lo1 < hi1)) {
            if (lo0 < hi0) {
                const uint32_t mid = lo0 + ((hi0 - lo0) >> 1);
                int c = 0;
                #pragma unroll
                for (int g = 0; g < NCH; ++g)
                    if (64 * g < cnt0) c += __popcll(__ballot(eo0[g] <= mid));
                if (c >= KMAX) hi0 = mid; else lo0 = mid + 1;
            }
            if (lo1 < hi1) {
                const uint32_t mid = lo1 + ((hi1 - lo1) >> 1);
                int c = 0;
                #pragma unroll
                for (int g = 0; g < NCH; ++g)
                    if (64 * g < cnt1) c += __popcll(__ballot(eo1[g] <= mid));
                if (c >= KMAX) hi1 = mid; else lo1 = mid + 1;
            }
        }
        const uint32_t T0 = lo0, T1 = lo1;

        int cLT0 = 0, cLE0 = 0, cLT1 = 0, cLE1 = 0;
        if (nd0) {
            #pragma unroll
            for (int g = 0; g < NCH; ++g) {
                cLT0 += __popcll(__ballot(eo0[g] < T0));
                cLE0 += __popcll(__ballot(eo0[g] <= T0));
            }
        }
        if (nd1) {
            #pragma unroll
            for (int g = 0; g < NCH; ++g) {
                cLT1 += __popcll(__ballot(eo1[g] < T1));
                cLE1 += __popcll(__ballot(eo1[g] <= T1));
            }
        }

        // fused tie resolution on j (exact; rarely taken)
        uint32_t J0 = 0xffffffffu, J1 = 0xffffffffu;
        const bool tb0 = nd0 && (cLE0 > KMAX), tb1 = nd1 && (cLE1 > KMAX);
        if (tb0 | tb1) {
            uint32_t jlo0 = 0u, jhi0 = tb0 ? (NPTS - 1) : 0u;
            uint32_t jlo1 = 0u, jhi1 = tb1 ? (NPTS - 1) : 0u;
            const int need0 = KMAX - cLT0, need1 = KMAX - cLT1;
            while ((jlo0 < jhi0) | (jlo1 < jhi1)) {
                if (jlo0 < jhi0) {
                    const uint32_t jmid = jlo0 + ((jhi0 - jlo0) >> 1);
                    int c = 0;
                    #pragma unroll
                    for (int g = 0; g < NCH; ++g)
                        if (64 * g < cnt0) c += __popcll(__ballot(eo0[g] == T0 && ej0[g] <= jmid));
                    if (c >= need0) jhi0 = jmid; else jlo0 = jmid + 1;
                }
                if (jlo1 < jhi1) {
                    const uint32_t jmid = jlo1 + ((jhi1 - jlo1) >> 1);
                    int c = 0;
                    #pragma unroll
                    for (int g = 0; g < NCH; ++g)
                        if (64 * g < cnt1) c += __popcll(__ballot(eo1[g] == T1 && ej1[g] <= jmid));
                    if (c >= need1) jhi1 = jmid; else jlo1 = jmid + 1;
                }
            }
            if (tb0) J0 = jlo0;
            if (tb1) J1 = jlo1;
        }

        // ballot-compact selected sets (order irrelevant for max-agg)
        if (nd0) {
            int sb = 0;
            #pragma unroll
            for (int g = 0; g < NCH; ++g) {
                if (64 * g < cnt0) {
                    const bool take = (eo0[g] < T0) || ((eo0[g] == T0) && (ej0[g] <= J0));
                    const ULL mk = __ballot(take);
                    if (take) s_nbr[0][sb + __popcll(mk & lmask)] = (int)ej0[g];
                    sb += __popcll(mk);
                }
            }
        }
        if (nd1) {
            int sb = 0;
            #pragma unroll
            for (int g = 0; g < NCH; ++g) {
                if (64 * g < cnt1) {
                    const bool take = (eo1[g] < T1) || ((eo1[g] == T1) && (ej1[g] <= J1));
                    const ULL mk = __ballot(take);
                    if (take) s_nbr[1][sb + __popcll(mk & lmask)] = (int)ej1[g];
                    sb += __popcll(mk);
                }
            }
        }
    }

    // ---- MFMA phase: hoisted dual af build, then shared-B MFMA ----
    const int mm[2] = { cnt0 < KMAX ? cnt0 : KMAX, cnt1 < KMAX ? cnt1 : KMAX };

    bf16x8 af[2][4][2];
    #pragma unroll
    for (int ci = 0; ci < 2; ++ci) {
        #pragma unroll
        for (int t = 0; t < 4; ++t) {
            const int row = t * 16 + r;
            const int j = s_nbr[ci][row];      // valid index even for row >= m
            const float4* Aj = (const float4*)(A + (size_t)j * HID1);
            #pragma unroll
            for (int kc = 0; kc < 2; ++kc) {
                const float4 a0 = Aj[kc * 8 + q * 2], a1 = Aj[kc * 8 + q * 2 + 1];
                bf16x8 v;
                v[0] = f2bf(fmaxf(a0.x - cv[ci][kc][0], 0.0f));
                v[1] = f2bf(fmaxf(a0.y - cv[ci][kc][1], 0.0f));
                v[2] = f2bf(fmaxf(a0.z - cv[ci][kc][2], 0.0f));
                v[3] = f2bf(fmaxf(a0.w - cv[ci][kc][3], 0.0f));
                v[4] = f2bf(fmaxf(a1.x - cv[ci][kc][4], 0.0f));
                v[5] = f2bf(fmaxf(a1.y - cv[ci][kc][5], 0.0f));
                v[6] = f2bf(fmaxf(a1.z - cv[ci][kc][6], 0.0f));
                v[7] = f2bf(fmaxf(a1.w - cv[ci][kc][7], 0.0f));
                af[ci][t][kc] = v;
            }
        }
    }

    // per col-tile: one B-fragment load feeds both centroids (16 MFMA / load)
    #pragma unroll
    for (int cb = 0; cb < 8; ++cb) {
        f32x4 acc[2][4];
        #pragma unroll
        for (int ci = 0; ci < 2; ++ci)
            #pragma unroll
            for (int t = 0; t < 4; ++t) acc[ci][t] = (f32x4){0.f, 0.f, 0.f, 0.f};

        #pragma unroll
        for (int kc = 0; kc < 2; ++kc) {
            const bf16x8 bf =
                *(const bf16x8*)&W2T[(cb * 16 + r) * HID1 + kc * 32 + q * 8];
            #pragma unroll
            for (int ci = 0; ci < 2; ++ci)
                #pragma unroll
                for (int t = 0; t < 4; ++t)
                    acc[ci][t] = __builtin_amdgcn_mfma_f32_16x16x32_bf16(
                        af[ci][t][kc], bf, acc[ci][t], 0, 0, 0);
        }

        const int c = cb * 16 + r;
        #pragma unroll
        for (int ci = 0; ci < 2; ++ci) {
            float v = -FLT_MAX;
            #pragma unroll
            for (int t = 0; t < 4; ++t) {
                const int nb = t * 16 + q * 4; // D: col=l&15, row=(l>>4)*4+reg
                #pragma unroll
                for (int reg = 0; reg < 4; ++reg)
                    if (nb + reg < mm[ci]) v = fmaxf(v, acc[ci][t][reg]);
            }
            v = fmaxf(v, __shfl_xor(v, 16));
            v = fmaxf(v, __shfl_xor(v, 32));
            if (q == 0)
                out[(size_t)(i0 + ci) * HID2 + c] = fmaxf(v + b2[c], 0.0f);
        }
    }
}

extern "C" void kernel_launch(void* const* d_in, const int* in_sizes, int n_in,
                              void* d_out, int out_size, void* d_ws, size_t ws_size,
                              hipStream_t stream) {
    const float* x     = (const float*)d_in[0];
    const float* pos   = (const float*)d_in[1];
    const int*   batch = (const int*)d_in[2];
    const float* W1    = (const float*)d_in[3];
    const float* b1    = (const float*)d_in[4];
    const float* W2    = (const float*)d_in[5];
    const float* b2    = (const float*)d_in[6];
    float* out = (float*)d_out;

    float*  A    = (float*)d_ws;                          // 2 MB
    float*  C    = A + (size_t)NPTS * HID1;               // 2 MB
    float4* P4   = (float4*)(C + (size_t)NPTS * HID1);    // 128 KB (16B aligned)
    unsigned short* W2T = (unsigned short*)(P4 + NPTS);   // 16 KB

    hipLaunchKernelGGL(prep_kernel, dim3(NPTS * HID1 / 256), dim3(256), 0, stream,
                       x, pos, batch, W1, b1, W2, A, C, P4, W2T, out);
    hipLaunchKernelGGL(pointconv_kernel, dim3(NPTS / 2), dim3(64), 0, stream,
                       batch, W2T, b2, A, C, P4, out);
}

// Round 18
// 48.696 us; speedup vs baseline: 1.2457x; 1.2457x over previous
//
#include <hip/hip_runtime.h>
#include <hip/hip_bf16.h>
#include <float.h>
#include <stdint.h>

#define NPTS 8192
#define SEG  2048
#define CF   16
#define HID1 64
#define HID2 128
#define KMAX 64
#define R2   0.49f
#define CAP  384          // max in-radius candidates ~170 expected; wide margin
#define NCH  6            // CAP / 64

typedef unsigned long long ULL;
typedef short bf16x8 __attribute__((ext_vector_type(8)));
typedef float f32x4  __attribute__((ext_vector_type(4)));

__device__ __forceinline__ uint32_t f2ord(float f) {
    uint32_t u = __float_as_uint(f);
    return (u & 0x80000000u) ? ~u : (u | 0x80000000u);
}

// native RNE f32 -> bf16 (hardware v_cvt; identical bits to manual RNE for finite)
__device__ __forceinline__ short f2bf(float f) {
    __hip_bfloat16 h = __float2bfloat16(f);
    union { __hip_bfloat16 b; short s; } u; u.b = h;
    return u.s;
}

// ---- prep: A = x@W1[:16] + pos@W1[16:19] + b1 ; C = pos@W1[16:19] ;
//      pos4 = (x,y,z,sq) ; W2T[c][k] = bf16(W2[k][c]) ; echo pos/batch ----
__global__ __launch_bounds__(256) void prep_kernel(
    const float* __restrict__ x, const float* __restrict__ pos,
    const int* __restrict__ batch,
    const float* __restrict__ W1, const float* __restrict__ b1,
    const float* __restrict__ W2,
    float* __restrict__ A, float* __restrict__ C,
    float4* __restrict__ pos4, unsigned short* __restrict__ W2T,
    float* __restrict__ out)
{
    const int t = blockIdx.x * 256 + threadIdx.x;   // t < NPTS*64
    const int i = t >> 6, k = t & 63;

    const float px = pos[3 * i + 0], py = pos[3 * i + 1], pz = pos[3 * i + 2];
    float c = __fmul_rn(px, W1[16 * HID1 + k]);
    c = fmaf(py, W1[17 * HID1 + k], c);
    c = fmaf(pz, W1[18 * HID1 + k], c);

    float a = b1[k];
    #pragma unroll
    for (int cc = 0; cc < CF; ++cc)
        a = fmaf(x[i * CF + cc], W1[cc * HID1 + k], a);
    a += c;

    A[t] = a;
    C[t] = c;

    if (t < HID1 * HID2) {
        const int cc = t >> 6, kk = t & 63;      // W2T[c][k], c-stride 64
        W2T[t] = (unsigned short)f2bf(W2[kk * HID2 + cc]);
    }

    if (k == 0) {
        const float sq = __fadd_rn(__fadd_rn(__fmul_rn(px, px), __fmul_rn(py, py)),
                                   __fmul_rn(pz, pz));
        pos4[i] = make_float4(px, py, pz, sq);
    }
    if (k < 3) out[NPTS * HID2 + 3 * i + k] = pos[3 * i + k];
    if (k == 3) out[NPTS * HID2 + NPTS * 3 + i] = (float)batch[i];
}

// ---- 1 wave = 2 centroids: hoisted cv loads -> prefetch-1 shared-load scan ->
//      fused dual 4-ARY threshold select -> hoisted dual af build -> shared-B MFMA ----
__global__ __launch_bounds__(64, 3) void pointconv_kernel(
    const int* __restrict__ batch,
    const unsigned short* __restrict__ W2T, const float* __restrict__ b2,
    const float* __restrict__ A, const float* __restrict__ C,
    const float4* __restrict__ pos4, float* __restrict__ out)
{
    __shared__ ULL s_key[2][CAP];   // 6 KB
    __shared__ int s_nbr[2][KMAX];  // 512 B

    const int l  = threadIdx.x;
    const int i0 = blockIdx.x * 2;          // pair shares a segment (2048 even)
    const int r = l & 15, q = l >> 4;

    const float4 cw0 = pos4[i0], cw1 = pos4[i0 + 1];
    const int seg0 = batch[i0] * SEG;
    const ULL lmask = (1ull << l) - 1ull;

    // hoisted C-row loads (independent of everything below; overlap with scan)
    float cv[2][2][8];
    #pragma unroll
    for (int ci = 0; ci < 2; ++ci) {
        const float4* Cv = (const float4*)(C + (size_t)(i0 + ci) * HID1);
        #pragma unroll
        for (int kc = 0; kc < 2; ++kc) {
            const float4 c0 = Cv[kc * 8 + q * 2], c1 = Cv[kc * 8 + q * 2 + 1];
            cv[ci][kc][0] = c0.x; cv[ci][kc][1] = c0.y;
            cv[ci][kc][2] = c0.z; cv[ci][kc][3] = c0.w;
            cv[ci][kc][4] = c1.x; cv[ci][kc][5] = c1.y;
            cv[ci][kc][6] = c1.z; cv[ci][kc][7] = c1.w;
        }
    }

    // shared-load scan with one-iteration-ahead register prefetch
    int cnt0 = 0, cnt1 = 0;
    float4 pj = pos4[seg0 + l];
    #pragma unroll 4
    for (int it = 0; it < SEG / 64; ++it) {
        const float4 cur = pj;
        if (it + 1 < SEG / 64) pj = pos4[seg0 + (it + 1) * 64 + l];
        const int j = seg0 + it * 64 + l;
        const float dot0 = fmaf(cw0.z, cur.z, fmaf(cw0.y, cur.y, __fmul_rn(cw0.x, cur.x)));
        const float d20  = __fsub_rn(__fadd_rn(cw0.w, cur.w), __fmul_rn(2.0f, dot0));
        const float dot1 = fmaf(cw1.z, cur.z, fmaf(cw1.y, cur.y, __fmul_rn(cw1.x, cur.x)));
        const float d21  = __fsub_rn(__fadd_rn(cw1.w, cur.w), __fmul_rn(2.0f, dot1));
        const bool h0 = (d20 <= R2), h1 = (d21 <= R2);
        const ULL m0 = __ballot(h0), m1 = __ballot(h1);
        if (h0) {
            const int p = cnt0 + __popcll(m0 & lmask);
            if (p < CAP) s_key[0][p] = ((ULL)f2ord(d20) << 32) | (unsigned)j;
        }
        cnt0 += __popcll(m0);
        if (h1) {
            const int p = cnt1 + __popcll(m1 & lmask);
            if (p < CAP) s_key[1][p] = ((ULL)f2ord(d21) << 32) | (unsigned)j;
        }
        cnt1 += __popcll(m1);
    }
    if (cnt0 > CAP) cnt0 = CAP;
    if (cnt1 > CAP) cnt1 = CAP;
    const bool nd0 = cnt0 > KMAX, nd1 = cnt1 > KMAX;

    uint32_t eo0[NCH], ej0[NCH], eo1[NCH], ej1[NCH];
    if (!nd0) {
        if (l < KMAX) s_nbr[0][l] = (l < cnt0) ? (int)(s_key[0][l] & 0xffffffffu) : i0;
    } else {
        #pragma unroll
        for (int g = 0; g < NCH; ++g) {
            eo0[g] = 0xffffffffu; ej0[g] = 0xffffffffu;
            if (64 * g < cnt0) {
                const int e = l + 64 * g;
                if (e < cnt0) {
                    const ULL kk = s_key[0][e];
                    eo0[g] = (uint32_t)(kk >> 32);
                    ej0[g] = (uint32_t)(kk & 0xffffffffu);
                }
            }
        }
    }
    if (!nd1) {
        if (l < KMAX) s_nbr[1][l] = (l < cnt1) ? (int)(s_key[1][l] & 0xffffffffu) : i0 + 1;
    } else {
        #pragma unroll
        for (int g = 0; g < NCH; ++g) {
            eo1[g] = 0xffffffffu; ej1[g] = 0xffffffffu;
            if (64 * g < cnt1) {
                const int e = l + 64 * g;
                if (e < cnt1) {
                    const ULL kk = s_key[1][e];
                    eo1[g] = (uint32_t)(kk >> 32);
                    ej1[g] = (uint32_t)(kk & 0xffffffffu);
                }
            }
        }
    }

    if (nd0 || nd1) {
        const uint32_t ORDR2 = 0x80000000u | __float_as_uint(R2);
        // fused dual 4-ARY search: 3 probes/iter, range shrinks x4, <=16 iters.
        // Invariant: count(<lo) < K and count(<=hi) >= K.
        uint32_t lo0 = 0u, hi0 = nd0 ? ORDR2 : 0u;
        uint32_t lo1 = 0u, hi1 = nd1 ? ORDR2 : 0u;
        while ((lo0 < hi0) | (lo1 < hi1)) {
            if (lo0 < hi0) {
                const uint32_t sp = hi0 - lo0;
                const uint32_t m1 = lo0 + (sp >> 2);
                const uint32_t m2 = lo0 + (sp >> 1);
                const uint32_t m3 = lo0 + sp - (sp >> 2);
                int c1 = 0, c2 = 0, c3 = 0;
                #pragma unroll
                for (int g = 0; g < NCH; ++g) {
                    if (64 * g < cnt0) {
                        c1 += __popcll(__ballot(eo0[g] <= m1));
                        c2 += __popcll(__ballot(eo0[g] <= m2));
                        c3 += __popcll(__ballot(eo0[g] <= m3));
                    }
                }
                if      (c1 >= KMAX) hi0 = m1;
                else if (c2 >= KMAX) { lo0 = m1 + 1; hi0 = m2; }
                else if (c3 >= KMAX) { lo0 = m2 + 1; hi0 = m3; }
                else                 lo0 = m3 + 1;
            }
            if (lo1 < hi1) {
                const uint32_t sp = hi1 - lo1;
                const uint32_t m1 = lo1 + (sp >> 2);
                const uint32_t m2 = lo1 + (sp >> 1);
                const uint32_t m3 = lo1 + sp - (sp >> 2);
                int c1 = 0, c2 = 0, c3 = 0;
                #pragma unroll
                for (int g = 0; g < NCH; ++g) {
                    if (64 * g < cnt1) {
                        c1 += __popcll(__ballot(eo1[g] <= m1));
                        c2 += __popcll(__ballot(eo1[g] <= m2));
                        c3 += __popcll(__ballot(eo1[g] <= m3));
                    }
                }
                if      (c1 >= KMAX) hi1 = m1;
                else if (c2 >= KMAX) { lo1 = m1 + 1; hi1 = m2; }
                else if (c3 >= KMAX) { lo1 = m2 + 1; hi1 = m3; }
                else                 lo1 = m3 + 1;
            }
        }
        const uint32_t T0 = lo0, T1 = lo1;

        int cLT0 = 0, cLE0 = 0, cLT1 = 0, cLE1 = 0;
        if (nd0) {
            #pragma unroll
            for (int g = 0; g < NCH; ++g) {
                cLT0 += __popcll(__ballot(eo0[g] < T0));
                cLE0 += __popcll(__ballot(eo0[g] <= T0));
            }
        }
        if (nd1) {
            #pragma unroll
            for (int g = 0; g < NCH; ++g) {
                cLT1 += __popcll(__ballot(eo1[g] < T1));
                cLE1 += __popcll(__ballot(eo1[g] <= T1));
            }
        }

        // fused tie resolution on j (exact; rarely taken)
        uint32_t J0 = 0xffffffffu, J1 = 0xffffffffu;
        const bool tb0 = nd0 && (cLE0 > KMAX), tb1 = nd1 && (cLE1 > KMAX);
        if (tb0 | tb1) {
            uint32_t jlo0 = 0u, jhi0 = tb0 ? (NPTS - 1) : 0u;
            uint32_t jlo1 = 0u, jhi1 = tb1 ? (NPTS - 1) : 0u;
            const int need0 = KMAX - cLT0, need1 = KMAX - cLT1;
            while ((jlo0 < jhi0) | (jlo1 < jhi1)) {
                if (jlo0 < jhi0) {
                    const uint32_t jmid = jlo0 + ((jhi0 - jlo0) >> 1);
                    int c = 0;
                    #pragma unroll
                    for (int g = 0; g < NCH; ++g)
                        if (64 * g < cnt0) c += __popcll(__ballot(eo0[g] == T0 && ej0[g] <= jmid));
                    if (c >= need0) jhi0 = jmid; else jlo0 = jmid + 1;
                }
                if (jlo1 < jhi1) {
                    const uint32_t jmid = jlo1 + ((jhi1 - jlo1) >> 1);
                    int c = 0;
                    #pragma unroll
                    for (int g = 0; g < NCH; ++g)
                        if (64 * g < cnt1) c += __popcll(__ballot(eo1[g] == T1 && ej1[g] <= jmid));
                    if (c >= need1) jhi1 = jmid; else jlo1 = jmid + 1;
                }
            }
            if (tb0) J0 = jlo0;
            if (tb1) J1 = jlo1;
        }

        // ballot-compact selected sets (order irrelevant for max-agg)
        if (nd0) {
            int sb = 0;
            #pragma unroll
            for (int g = 0; g < NCH; ++g) {
                if (64 * g < cnt0) {
                    const bool take = (eo0[g] < T0) || ((eo0[g] == T0) && (ej0[g] <= J0));
                    const ULL mk = __ballot(take);
                    if (take) s_nbr[0][sb + __popcll(mk & lmask)] = (int)ej0[g];
                    sb += __popcll(mk);
                }
            }
        }
        if (nd1) {
            int sb = 0;
            #pragma unroll
            for (int g = 0; g < NCH; ++g) {
                if (64 * g < cnt1) {
                    const bool take = (eo1[g] < T1) || ((eo1[g] == T1) && (ej1[g] <= J1));
                    const ULL mk = __ballot(take);
                    if (take) s_nbr[1][sb + __popcll(mk & lmask)] = (int)ej1[g];
                    sb += __popcll(mk);
                }
            }
        }
    }

    // ---- MFMA phase: hoisted dual af build, then shared-B MFMA ----
    const int mm[2] = { cnt0 < KMAX ? cnt0 : KMAX, cnt1 < KMAX ? cnt1 : KMAX };

    bf16x8 af[2][4][2];
    #pragma unroll
    for (int ci = 0; ci < 2; ++ci) {
        #pragma unroll
        for (int t = 0; t < 4; ++t) {
            const int row = t * 16 + r;
            const int j = s_nbr[ci][row];      // valid index even for row >= m
            const float4* Aj = (const float4*)(A + (size_t)j * HID1);
            #pragma unroll
            for (int kc = 0; kc < 2; ++kc) {
                const float4 a0 = Aj[kc * 8 + q * 2], a1 = Aj[kc * 8 + q * 2 + 1];
                bf16x8 v;
                v[0] = f2bf(fmaxf(a0.x - cv[ci][kc][0], 0.0f));
                v[1] = f2bf(fmaxf(a0.y - cv[ci][kc][1], 0.0f));
                v[2] = f2bf(fmaxf(a0.z - cv[ci][kc][2], 0.0f));
                v[3] = f2bf(fmaxf(a0.w - cv[ci][kc][3], 0.0f));
                v[4] = f2bf(fmaxf(a1.x - cv[ci][kc][4], 0.0f));
                v[5] = f2bf(fmaxf(a1.y - cv[ci][kc][5], 0.0f));
                v[6] = f2bf(fmaxf(a1.z - cv[ci][kc][6], 0.0f));
                v[7] = f2bf(fmaxf(a1.w - cv[ci][kc][7], 0.0f));
                af[ci][t][kc] = v;
            }
        }
    }

    // per col-tile: one B-fragment load feeds both centroids (16 MFMA / load)
    #pragma unroll
    for (int cb = 0; cb < 8; ++cb) {
        f32x4 acc[2][4];
        #pragma unroll
        for (int ci = 0; ci < 2; ++ci)
            #pragma unroll
            for (int t = 0; t < 4; ++t) acc[ci][t] = (f32x4){0.f, 0.f, 0.f, 0.f};

        #pragma unroll
        for (int kc = 0; kc < 2; ++kc) {
            const bf16x8 bf =
                *(const bf16x8*)&W2T[(cb * 16 + r) * HID1 + kc * 32 + q * 8];
            #pragma unroll
            for (int ci = 0; ci < 2; ++ci)
                #pragma unroll
                for (int t = 0; t < 4; ++t)
                    acc[ci][t] = __builtin_amdgcn_mfma_f32_16x16x32_bf16(
                        af[ci][t][kc], bf, acc[ci][t], 0, 0, 0);
        }

        const int c = cb * 16 + r;
        #pragma unroll
        for (int ci = 0; ci < 2; ++ci) {
            float v = -FLT_MAX;
            #pragma unroll
            for (int t = 0; t < 4; ++t) {
                const int nb = t * 16 + q * 4; // D: col=l&15, row=(l>>4)*4+reg
                #pragma unroll
                for (int reg = 0; reg < 4; ++reg)
                    if (nb + reg < mm[ci]) v = fmaxf(v, acc[ci][t][reg]);
            }
            v = fmaxf(v, __shfl_xor(v, 16));
            v = fmaxf(v, __shfl_xor(v, 32));
            if (q == 0)
                out[(size_t)(i0 + ci) * HID2 + c] = fmaxf(v + b2[c], 0.0f);
        }
    }
}

extern "C" void kernel_launch(void* const* d_in, const int* in_sizes, int n_in,
                              void* d_out, int out_size, void* d_ws, size_t ws_size,
                              hipStream_t stream) {
    const float* x     = (const float*)d_in[0];
    const float* pos   = (const float*)d_in[1];
    const int*   batch = (const int*)d_in[2];
    const float* W1    = (const float*)d_in[3];
    const float* b1    = (const float*)d_in[4];
    const float* W2    = (const float*)d_in[5];
    const float* b2    = (const float*)d_in[6];
    float* out = (float*)d_out;

    float*  A    = (float*)d_ws;                          // 2 MB
    float*  C    = A + (size_t)NPTS * HID1;               // 2 MB
    float4* P4   = (float4*)(C + (size_t)NPTS * HID1);    // 128 KB (16B aligned)
    unsigned short* W2T = (unsigned short*)(P4 + NPTS);   // 16 KB

    hipLaunchKernelGGL(prep_kernel, dim3(NPTS * HID1 / 256), dim3(256), 0, stream,
                       x, pos, batch, W1, b1, W2, A, C, P4, W2T, out);
    hipLaunchKernelGGL(pointconv_kernel, dim3(NPTS / 2), dim3(64), 0, stream,
                       batch, W2T, b2, A, C, P4, out);
}